// Round 14
// baseline (338.834 us; speedup 1.0000x reference)
//
#include <hip/hip_runtime.h>
#include <hip/hip_bf16.h>
#include <stdint.h>

#define B_ 8
#define NTOK 7225
#define MTOT (B_*NTOK)      // 57800
#define MROWS 58368         // padded rows for all M-row buffers (228*256)
#define MT_FULL 226         // ceil(57800/256)
#define MT_BATCH 29         // ceil(7225/256)
#define MLP_TILES 904       // ceil(57800/64)

typedef unsigned short u16;
typedef u16 u16x8 __attribute__((ext_vector_type(8)));
typedef u16 u16x4 __attribute__((ext_vector_type(4)));
typedef __bf16 bf16x8 __attribute__((ext_vector_type(8)));
typedef float f32x4 __attribute__((ext_vector_type(4)));

__device__ inline float bf2f(u16 u){ union{float f;uint32_t i;}c; c.i=((uint32_t)u)<<16; return c.f; }
__device__ inline u16 f2bf(float f){ union{float f;uint32_t i;}c; c.f=f; uint32_t x=c.i;
                                     return (u16)((x + 0x7fffu + ((x>>16)&1u))>>16); }
__device__ inline uint32_t cvt_pk_bf16(float a, float b){
  uint32_t r; asm("v_cvt_pk_bf16_f32 %0, %1, %2" : "=v"(r) : "v"(a), "v"(b)); return r;
}
// fast tanh-gelu: 0.5x(1+tanh t) == x * (1 - 1/(exp(2t)+1))
__device__ inline float gelu_f(float x){
  float t = 0.7978845608028654f * x * (1.0f + 0.044715f*x*x);
  float e = __expf(2.0f*t);
  return x * (1.0f - __builtin_amdgcn_rcpf(e + 1.0f));
}

__device__ inline void gload_lds16(const u16* g, u16* l) {
  __builtin_amdgcn_global_load_lds(
      (__attribute__((address_space(1))) void*)(const_cast<u16*>(g)),
      (__attribute__((address_space(3))) void*)(l), 16, 0, 0);
}

// ============ 256x256-tile GEMM (R7 schedule) + coalesced bf16 epilogue (R10) ============
// EPI 0: bf16 = acc+bias (LDS-bounce, 512B-row coalesced stores)
// EPI 3: f32 out = v = acc+bias+res AND bf16 x2 = LayerNorm_row(v)*g2+b2 (fused LN2)
template<int EPI>
__global__ __launch_bounds__(512, 2)
void gemm256(const u16* __restrict__ A, int lda,
             const u16* __restrict__ Bm, int ldb, long bStride,
             const float* __restrict__ bias, int biasStride,
             const float* __restrict__ res,
             void* __restrict__ outp, int ldo,
             int K, int rowsValid, int batchRowStride,
             const float* __restrict__ g2, const float* __restrict__ b2,
             u16* __restrict__ x2out)
{
  __shared__ alignas(16) u16 lds[65536];   // A: [0,32768), B: [32768,65536)
  const int tid = threadIdx.x;
  const int wid = tid >> 6, lane = tid & 63;
  const int wm = wid >> 2, wn = wid & 3;

  const int gx = gridDim.x, gy = gridDim.y;
  const int n = gx * gy;
  const int flat = blockIdx.y * gx + blockIdx.x;
  const int qq = n >> 3, rr = n & 7;
  const int xcd = flat & 7, pos = flat >> 3;
  const int swz = (xcd < rr ? xcd*(qq+1) : rr*(qq+1) + (xcd-rr)*qq) + pos;
  const int bx = swz / gy, by = swz % gy;
  const int bz = blockIdx.z;

  const long rowBase = (long)bz * batchRowStride + (long)bx * 256;
  const int colBase = by * 256;
  const u16* Bp = Bm + (long)bz * bStride;
  const float* biasP = bias + bz * biasStride;

  const int srow = lane >> 2;
  const int scol = ((lane & 3) ^ ((lane >> 3) & 3)) * 8;
  const int NT = K >> 6;

  auto stageHalf = [&](int bf, int kt, int sel) {
    const int sub = sel >> 1;
    const int k0 = (kt << 6) + sub*32 + scol;
    u16* base = lds + ((sel & 1) ? 32768 : 0) + (bf*2 + sub)*8192;
#pragma unroll
    for (int i = 0; i < 2; ++i) {
      const int r0 = (wid*2 + i)*16;
      if ((sel & 1) == 0)
        gload_lds16(A + (rowBase + r0 + srow)*(long)lda + k0, base + r0*32);
      else
        gload_lds16(Bp + (long)(colBase + r0 + srow)*ldb + k0, base + r0*32);
    }
  };

  f32x4 acc[8][4] = {};
  bf16x8 afr[4], bfr[4];
  const int lr = lane & 15;
  const int sl = lane >> 4;
  const int sp = (sl ^ ((lr >> 1) & 3)) * 8;

  stageHalf(0, 0, 0); stageHalf(0, 0, 1); stageHalf(0, 0, 2); stageHalf(0, 0, 3);

  for (int kt = 0; kt < NT; ++kt) {
    const int bf = kt & 1;
    const bool st = (kt + 1 < NT);
#pragma unroll
    for (int ph = 0; ph < 4; ++ph) {
      const int sub = ph >> 1, mh = ph & 1;
      if (ph == 0) {
        asm volatile("s_waitcnt vmcnt(4)" ::: "memory");
      } else if (ph == 2) {
        if (kt == NT - 1) asm volatile("s_waitcnt vmcnt(0)" ::: "memory");
        else              asm volatile("s_waitcnt vmcnt(4)" ::: "memory");
      } else {
        asm volatile("s_waitcnt vmcnt(6)" ::: "memory");
      }
      __builtin_amdgcn_s_barrier();
      const u16* Ab = lds + (bf*2 + sub)*8192;
      const u16* Bb = lds + 32768 + (bf*2 + sub)*8192;
      if (mh == 0) {
#pragma unroll
        for (int ni = 0; ni < 4; ++ni)
          bfr[ni] = *reinterpret_cast<const bf16x8*>(&Bb[(wn*64 + ni*16 + lr)*32 + sp]);
      }
#pragma unroll
      for (int i = 0; i < 4; ++i)
        afr[i] = *reinterpret_cast<const bf16x8*>(&Ab[(wm*128 + (mh*4 + i)*16 + lr)*32 + sp]);
      if (st) stageHalf(bf ^ 1, kt + 1, ph);
      asm volatile("s_waitcnt lgkmcnt(0)" ::: "memory");
      __builtin_amdgcn_sched_barrier(0);
      __builtin_amdgcn_s_setprio(1);
#pragma unroll
      for (int i = 0; i < 4; ++i)
#pragma unroll
        for (int ni = 0; ni < 4; ++ni)
          acc[mh*4 + i][ni] =
              __builtin_amdgcn_mfma_f32_16x16x32_bf16(bfr[ni], afr[i], acc[mh*4 + i][ni], 0, 0, 0);
      __builtin_amdgcn_s_setprio(0);
    }
  }

  const int cq = sl * 4;
  if (EPI <= 1) {
    __syncthreads();
#pragma unroll
    for (int mi = 0; mi < 8; ++mi) {
      const int r = wm*128 + mi*16 + lr;
#pragma unroll
      for (int ni = 0; ni < 4; ++ni) {
        const int c = wn*64 + ni*16 + cq;
        f32x4 v = acc[mi][ni] + *reinterpret_cast<const f32x4*>(&biasP[colBase + c]);
        uint2 pk;
        if (EPI == 1) { pk.x = cvt_pk_bf16(gelu_f(v[0]), gelu_f(v[1]));
                        pk.y = cvt_pk_bf16(gelu_f(v[2]), gelu_f(v[3])); }
        else          { pk.x = cvt_pk_bf16(v[0], v[1]); pk.y = cvt_pk_bf16(v[2], v[3]); }
        const int unit = ((c >> 3) ^ (r & 7));
        *reinterpret_cast<uint2*>(lds + r*256 + unit*8 + (c & 7)) = pk;
      }
    }
    __syncthreads();
#pragma unroll
    for (int p = 0; p < 16; ++p) {
      const int idx = p*512 + tid;
      const int r = idx >> 5, u = idx & 31;
      const int phys = u ^ (r & 7);
      u16x8 val = *reinterpret_cast<const u16x8*>(lds + r*256 + phys*8);
      *reinterpret_cast<u16x8*>((u16*)outp + (rowBase + r)*(long)ldo + colBase + u*8) = val;
    }
  } else {
    // EPI 3: v = acc + be + fx; out=v (f32); x2 = LN_row(v)*g2+b2 (bf16). colBase==0, ldo==256.
    float* red = reinterpret_cast<float*>(lds);
    __syncthreads();
#pragma unroll
    for (int mi = 0; mi < 8; ++mi) {
      const int r = wm*128 + mi*16 + lr;
      const bool valid = (bx*256 + r < rowsValid);
      const long grow = rowBase + r;
      float s_r = 0.f, q_r = 0.f;
#pragma unroll
      for (int ni = 0; ni < 4; ++ni) {
        const int c0 = wn*64 + ni*16 + cq;
        f32x4 rv = valid ? *reinterpret_cast<const f32x4*>((const float*)res + grow*256 + c0)
                         : f32x4{0.f,0.f,0.f,0.f};
        f32x4 v = acc[mi][ni] + *reinterpret_cast<const f32x4*>(&biasP[c0]) + rv;
        acc[mi][ni] = v;
        s_r += v[0]+v[1]+v[2]+v[3];
        q_r += v[0]*v[0]+v[1]*v[1]+v[2]*v[2]+v[3]*v[3];
      }
      s_r += __shfl_xor(s_r, 16); s_r += __shfl_xor(s_r, 32);
      q_r += __shfl_xor(q_r, 16); q_r += __shfl_xor(q_r, 32);
      if (sl == 0) {
        red[       (wm*4 + wn)*128 + mi*16 + lr] = s_r;
        red[1024 + (wm*4 + wn)*128 + mi*16 + lr] = q_r;
      }
    }
    __syncthreads();
#pragma unroll
    for (int mi = 0; mi < 8; ++mi) {
      const int r = wm*128 + mi*16 + lr;
      if (bx*256 + r >= rowsValid) continue;
      const long grow = rowBase + r;
      const int rb = wm*4*128 + mi*16 + lr;
      float s_t = red[rb] + red[rb+128] + red[rb+256] + red[rb+384];
      float q_t = red[1024+rb] + red[1024+rb+128] + red[1024+rb+256] + red[1024+rb+384];
      const float m = s_t * (1.0f/256.0f);
      const float var = q_t * (1.0f/256.0f) - m*m;
      const float rs = rsqrtf(var + 1e-5f);
#pragma unroll
      for (int ni = 0; ni < 4; ++ni) {
        const int c0 = wn*64 + ni*16 + cq;
        const long oidx = grow*256 + c0;
        f32x4 v = acc[mi][ni];
        *reinterpret_cast<f32x4*>((float*)outp + oidx) = v;
        f32x4 gv = *reinterpret_cast<const f32x4*>(&g2[c0]);
        f32x4 bv = *reinterpret_cast<const f32x4*>(&b2[c0]);
        f32x4 xn = (v - m) * rs * gv + bv;
        uint2 pk; pk.x = cvt_pk_bf16(xn[0], xn[1]); pk.y = cvt_pk_bf16(xn[2], xn[3]);
        *reinterpret_cast<uint2*>(x2out + oidx) = pk;
      }
    }
  }
}

// ============ fused MLP v4: v2's serial schedule at 2 blocks/CU (72KB LDS) ============
// out += gelu(x2@W1+b1)@W2 + b2.  M-tile 64, 512 thr = 8 waves (2M x 4N), chunk = 64 H-cols
// (16 chunks). LDS: Xs 32K + Wbuf 32K (W1c/W2c time-shared) + Hs 8K = 72K -> 2 blocks/CU.
// The serial vmcnt(0) weight-stage drains (v2-proven-correct) now overlap the co-resident
// block's MFMA phases (m114 TLP — the only mechanism that has consistently paid all session).
// Per chunk: gemm1 (Xs@W1c^T, K=256) -> gelu->Hs -> lgkm+barrier [Wbuf free, Hs published]
// -> stageW2 -> vmcnt(0)+barrier -> gemm2 (Hs@W2c^T accum, K=64) -> barrier [Wbuf free]
// -> stageW1(c+1) -> vmcnt(0)+barrier.
// Swizzles: 16B-unit XOR with (row & (units_per_row-1)) on both sides (R12-validated).
__global__ __launch_bounds__(512, 4)
void mlp_fused4(const u16* __restrict__ x2, const u16* __restrict__ W1t,
                const u16* __restrict__ W2t, const float* __restrict__ b1,
                const float* __restrict__ b2, float* __restrict__ outF,
                int rowsValid)
{
  __shared__ alignas(16) u16 Xs[64*256];   // 32K: [64 r][32 u], phys = u ^ (r&31)
  __shared__ alignas(16) u16 Wb[32768];    // 32K: W1c [64 hcol][32 u] or W2c [256 ocol][8 u]
  __shared__ alignas(16) u16 Hs[64*64];    //  8K: [64 r][8 u], phys = u ^ (r&7)
  const int tid = threadIdx.x;
  const int wid = tid >> 6, lane = tid & 63;
  const int wm = wid >> 2, wn = wid & 3;   // 2M x 4N
  const int lr = lane & 15, sl = lane >> 4;
  const long rowBase = (long)blockIdx.x * 64;

  // ---- staging (all coalesced; dest linear in unit id, global col pre-swizzled, G21)
#pragma unroll
  for (int i = 0; i < 4; ++i) {            // Xs: 2048 units
    const int u = i*512 + tid;
    const int r = u >> 5, pu = u & 31;
    gload_lds16(x2 + (rowBase + r)*256 + ((pu ^ (r & 31)) << 3), &Xs[u*8]);
  }
  auto stageW1 = [&](int c) {              // [64 hcol][256 k] = 32KB
#pragma unroll
    for (int i = 0; i < 4; ++i) {
      const int u = i*512 + tid;
      const int r = u >> 5, pu = u & 31;
      gload_lds16(W1t + (long)(c*64 + r)*256 + ((pu ^ (r & 31)) << 3), &Wb[u*8]);
    }
  };
  auto stageW2 = [&](int c) {              // [256 ocol][64 k] = 32KB
#pragma unroll
    for (int i = 0; i < 4; ++i) {
      const int u = i*512 + tid;
      const int r = u >> 3, pu = u & 7;
      gload_lds16(W2t + (long)r*1024 + c*64 + ((pu ^ (r & 7)) << 3), &Wb[u*8]);
    }
  };
  stageW1(0);
  asm volatile("s_waitcnt vmcnt(0)" ::: "memory");
  __syncthreads();

  f32x4 acc2[2][4] = {};
  for (int c = 0; c < 16; ++c) {
    // ---- gemm1: acc1[mi] = Xs rows (wm*32+mi*16) @ W1c^T (K=256); wave-n = 16 hcols
    f32x4 acc1[2] = {};
#pragma unroll
    for (int kk = 0; kk < 8; ++kk) {
      const int u = kk*4 + sl;
      const int rB = wn*16 + lr;
      bf16x8 wb = *reinterpret_cast<const bf16x8*>(&Wb[(rB*32 + (u ^ (rB & 31)))*8]);
#pragma unroll
      for (int mi = 0; mi < 2; ++mi) {
        const int rA = wm*32 + mi*16 + lr;
        bf16x8 xa = *reinterpret_cast<const bf16x8*>(&Xs[(rA*32 + (u ^ (rA & 31)))*8]);
        acc1[mi] = __builtin_amdgcn_mfma_f32_16x16x32_bf16(wb, xa, acc1[mi], 0, 0, 0);
      }
    }
    // ---- gelu + b1 -> Hs (row = rA, chunk-local col = wn*16 + sl*4)
    const float* b1c = b1 + c*64;
#pragma unroll
    for (int mi = 0; mi < 2; ++mi) {
      const int r = wm*32 + mi*16 + lr;
      const int col = wn*16 + sl*4;
      f32x4 v = acc1[mi] + *reinterpret_cast<const f32x4*>(&b1c[col]);
      uint2 pk; pk.x = cvt_pk_bf16(gelu_f(v[0]), gelu_f(v[1]));
      pk.y = cvt_pk_bf16(gelu_f(v[2]), gelu_f(v[3]));
      const int uw = (col >> 3) ^ (r & 7);
      *reinterpret_cast<uint2*>(&Hs[r*64 + uw*8 + (col & 7)]) = pk;
    }
    asm volatile("s_waitcnt lgkmcnt(0)" ::: "memory");
    __builtin_amdgcn_s_barrier();          // Wbuf free (gemm1 reads done) + Hs published
    stageW2(c);
    asm volatile("s_waitcnt vmcnt(0)" ::: "memory");
    __builtin_amdgcn_s_barrier();          // W2c visible to all waves

    // ---- gemm2: acc2[mi][nj] += Hs @ W2c^T (K=64); wave-n = 64 ocols
#pragma unroll
    for (int kk2 = 0; kk2 < 2; ++kk2) {
      const int u = kk2*4 + sl;
      bf16x8 ha[2];
#pragma unroll
      for (int mi = 0; mi < 2; ++mi) {
        const int r = wm*32 + mi*16 + lr;
        ha[mi] = *reinterpret_cast<const bf16x8*>(&Hs[(r*8 + (u ^ (r & 7)))*8]);
      }
#pragma unroll
      for (int nj = 0; nj < 4; ++nj) {
        const int rB = wn*64 + nj*16 + lr;
        bf16x8 wb = *reinterpret_cast<const bf16x8*>(&Wb[(rB*8 + (u ^ (rB & 7)))*8]);
#pragma unroll
        for (int mi = 0; mi < 2; ++mi)
          acc2[mi][nj] = __builtin_amdgcn_mfma_f32_16x16x32_bf16(wb, ha[mi], acc2[mi][nj], 0, 0, 0);
      }
    }
    __builtin_amdgcn_s_barrier();          // Wbuf free (gemm2 reads done)
    if (c + 1 < 16) {
      stageW1(c + 1);
      asm volatile("s_waitcnt vmcnt(0)" ::: "memory");
      __builtin_amdgcn_s_barrier();        // W1(c+1) visible
    }
  }
  // ---- epilogue: out += acc2 + b2 (f32 RMW, 16B/lane, row-guarded)
#pragma unroll
  for (int mi = 0; mi < 2; ++mi) {
    const int r = wm*32 + mi*16 + lr;
    if (rowBase + r < rowsValid) {
      float* orow = outF + (rowBase + r)*256;
#pragma unroll
      for (int nj = 0; nj < 4; ++nj) {
        const int col = wn*64 + nj*16 + sl*4;
        f32x4 v = acc2[mi][nj] + *reinterpret_cast<const f32x4*>(&b2[col])
                + *reinterpret_cast<const f32x4*>(&orow[col]);
        *reinterpret_cast<f32x4*>(&orow[col]) = v;
      }
    }
  }
}

// ---------------- LayerNorm over C=256, one wave per token, bf16 out ----------------
__global__ __launch_bounds__(256)
void ln_kernel(const float* __restrict__ in, const float* __restrict__ g,
               const float* __restrict__ bt, u16* __restrict__ out, int M)
{
  const int wv = threadIdx.x >> 6, lane = threadIdx.x & 63;
  const int t = blockIdx.x * 4 + wv;
  if (t >= M) return;
  const float4 x = reinterpret_cast<const float4*>(in + (long)t*256)[lane];
  float s = x.x + x.y + x.z + x.w;
  float q = x.x*x.x + x.y*x.y + x.z*x.z + x.w*x.w;
#pragma unroll
  for (int o = 32; o > 0; o >>= 1) { s += __shfl_xor(s, o); q += __shfl_xor(q, o); }
  const float m  = s * (1.0f/256.0f);
  const float var = q * (1.0f/256.0f) - m*m;
  const float rs = rsqrtf(var + 1e-5f);
  const float4 gv = reinterpret_cast<const float4*>(g)[lane];
  const float4 bv = reinterpret_cast<const float4*>(bt)[lane];
  uint2 o4;
  o4.x = cvt_pk_bf16((x.x - m)*rs*gv.x + bv.x, (x.y - m)*rs*gv.y + bv.y);
  o4.y = cvt_pk_bf16((x.z - m)*rs*gv.z + bv.z, (x.w - m)*rs*gv.w + bv.w);
  *reinterpret_cast<uint2*>(out + (long)t*256 + lane*4) = o4;
}

// -------- fused per-head LN(k), LN(v) + kv[b,h] += k^T v / N (atomic f32) --------
__global__ __launch_bounds__(256)
void kv_kernel(const u16* __restrict__ KV,
               const float* __restrict__ kg, const float* __restrict__ kb,
               const float* __restrict__ vg, const float* __restrict__ vb,
               float* __restrict__ kvout)
{
  const int bh = blockIdx.x, b = bh >> 3, h = bh & 7;
  const int tid = threadIdx.x;
  __shared__ u16 kls[256][32];
  __shared__ u16 vls[256][32];
  __shared__ float sg[4][32];
  if (tid < 32) {
    sg[0][tid] = kg[h*32 + tid];
    sg[1][tid] = kb[h*32 + tid];
    sg[2][tid] = vg[h*32 + tid];
    sg[3][tid] = vb[h*32 + tid];
  }
  const int d = tid >> 3, e0 = (tid & 7) * 4;
  float a0=0, a1=0, a2=0, a3=0;

  for (int sub = 0; sub < 2; ++sub) {
    const int r = blockIdx.y * 512 + sub * 256 + tid;
    __syncthreads();
    if (r < NTOK) {
      const u16* rowp = KV + (long)(b*NTOK + r)*512;
#pragma unroll
      for (int kv2 = 0; kv2 < 2; ++kv2) {
        const u16* p = rowp + (kv2 ? 256 : 0) + h*32;
        float xv[32]; float s = 0.f;
#pragma unroll
        for (int q4 = 0; q4 < 4; ++q4) {
          u16x8 u = *reinterpret_cast<const u16x8*>(p + q4*8);
#pragma unroll
          for (int j = 0; j < 8; ++j) { float f = bf2f(u[j]); xv[q4*8+j] = f; s += f; }
        }
        const float m = s * (1.0f/32.0f);
        float vv = 0.f;
#pragma unroll
        for (int j = 0; j < 32; ++j) { float d2 = xv[j]-m; vv += d2*d2; }
        const float rs = rsqrtf(vv*(1.0f/32.0f) + 1e-5f);
        const float* gg = sg[kv2 ? 2 : 0];
        const float* bb = sg[kv2 ? 3 : 1];
        u16 (*dst)[32] = kv2 ? vls : kls;
#pragma unroll
        for (int j = 0; j < 32; ++j) dst[tid][j] = f2bf((xv[j]-m)*rs*gg[j] + bb[j]);
      }
    } else {
#pragma unroll
      for (int j = 0; j < 32; ++j) { kls[tid][j] = 0; vls[tid][j] = 0; }
    }
    __syncthreads();
#pragma unroll 4
    for (int rr = 0; rr < 256; ++rr) {
      const float kd = bf2f(kls[rr][d]);
      u16x4 v4 = *reinterpret_cast<const u16x4*>(&vls[rr][e0]);
      a0 += kd * bf2f(v4[0]); a1 += kd * bf2f(v4[1]);
      a2 += kd * bf2f(v4[2]); a3 += kd * bf2f(v4[3]);
    }
  }
  const float sc = 1.0f / (float)NTOK;
  float* o = kvout + (long)bh*1024 + d*32 + e0;
  atomicAdd(o+0, a0*sc); atomicAdd(o+1, a1*sc);
  atomicAdd(o+2, a2*sc); atomicAdd(o+3, a3*sc);
}

// -------- Woe_t[b][c][j=h*32+d] = sum_e kv[b,h,d,e] * Wo[h*32+e][c] --------
__global__ __launch_bounds__(256)
void woeff_kernel(const float* __restrict__ kv, const float* __restrict__ Wo,
                  u16* __restrict__ Woet)
{
  const int b = blockIdx.x >> 8, c = blockIdx.x & 255;
  const int rtid = threadIdx.x;
  const int h = rtid >> 5, dd = rtid & 31;
  const float* kvp = kv + ((long)(b*8 + h)*32 + dd)*32;
  float s = 0.f;
#pragma unroll 8
  for (int e = 0; e < 32; ++e) s += kvp[e] * Wo[(h*32 + e)*256 + c];
  Woet[(long)(b*256 + c)*256 + rtid] = f2bf(s);
}

// -------- Watt[b][c][k] = sum_j Wq[k,j] * kvWo[b][j,c] --------
__global__ __launch_bounds__(256)
void watt_kernel(const u16* __restrict__ wq_bf, const u16* __restrict__ Woet,
                 u16* __restrict__ Watt)
{
  const int b = blockIdx.x >> 8, c = blockIdx.x & 255;
  const int k = threadIdx.x;
  const u16* wr = wq_bf + (long)k*256;
  const u16* er = Woet + ((long)(b*256 + c))*256;
  float s = 0.f;
#pragma unroll 4
  for (int j0 = 0; j0 < 256; j0 += 8) {
    u16x8 wv = *reinterpret_cast<const u16x8*>(wr + j0);
    u16x8 ev = *reinterpret_cast<const u16x8*>(er + j0);
#pragma unroll
    for (int j = 0; j < 8; ++j) s += bf2f(wv[j]) * bf2f(ev[j]);
  }
  Watt[((long)(b*256 + c))*256 + k] = f2bf(s);
}

// -------- be[b][c] = sum_j bq[j] * kvWo[b][j,c] + bo[c] --------
__global__ __launch_bounds__(256)
void be_kernel(const float* __restrict__ bq, const float* __restrict__ bo,
               const u16* __restrict__ Woet, float* __restrict__ be)
{
  const int b = blockIdx.x, c = threadIdx.x;
  const u16* er = Woet + ((long)(b*256 + c))*256;
  float s = bo[c];
#pragma unroll 4
  for (int j0 = 0; j0 < 256; j0 += 8) {
    u16x8 ev = *reinterpret_cast<const u16x8*>(er + j0);
#pragma unroll
    for (int j = 0; j < 8; ++j) s += bq[j0+j] * bf2f(ev[j]);
  }
  be[b*256 + c] = s;
}

// ---------------- mega-prep ----------------
__device__ void transpose_tile(const float* __restrict__ src, u16* __restrict__ dst,
                               int R, int C, int tcx, int trY)
{
  __shared__ float t[32][33];
  const int tc = tcx * 32, tr = trY * 32;
  const int lx = threadIdx.x & 31, ly = threadIdx.x >> 5;
#pragma unroll
  for (int i = 0; i < 32; i += 8)
    t[ly + i][lx] = src[(long)(tr + ly + i)*C + tc + lx];
  __syncthreads();
#pragma unroll
  for (int i = 0; i < 32; i += 8)
    dst[(long)(tc + ly + i)*R + tr + lx] = f2bf(t[lx][ly + i]);
}

__global__ __launch_bounds__(256)
void prep_kernel(const float* __restrict__ Wk, const float* __restrict__ Wv,
                 const float* __restrict__ W1, const float* __restrict__ W2,
                 const float* __restrict__ Wq,
                 const float* __restrict__ bk, const float* __restrict__ bv,
                 u16* __restrict__ Wkv_t, u16* __restrict__ W1_t, u16* __restrict__ W2_t,
                 u16* __restrict__ wq_bf, float* __restrict__ kvb, float* __restrict__ bkv)
{
  int b = blockIdx.x;
  if (b < 256)      { transpose_tile(W1, W1_t, 256, 1024, b & 31, b >> 5); }
  else if (b < 512) { b -= 256; transpose_tile(W2, W2_t, 1024, 256, b & 7, b >> 3); }
  else if (b < 576) { b -= 512; transpose_tile(Wk, Wkv_t,         256, 256, b & 7, b >> 3); }
  else if (b < 640) { b -= 576; transpose_tile(Wv, Wkv_t + 65536, 256, 256, b & 7, b >> 3); }
  else if (b < 648) {
    const int base = (b - 640) * 8192 + threadIdx.x;
#pragma unroll
    for (int i = 0; i < 32; ++i) wq_bf[base + i*256] = f2bf(Wq[base + i*256]);
  } else if (b < 656) {
    const int base = (b - 648) * 8192 + threadIdx.x;
#pragma unroll
    for (int i = 0; i < 32; ++i) kvb[base + i*256] = 0.f;
  } else {
    const int i = threadIdx.x;
    bkv[i] = bk[i]; bkv[256 + i] = bv[i];
  }
}

// ---------------- launch ----------------
extern "C" void kernel_launch(void* const* d_in, const int* in_sizes, int n_in,
                              void* d_out, int out_size, void* d_ws, size_t ws_size,
                              hipStream_t stream)
{
  const float* fx    = (const float*)d_in[0];
  const float* ln1_g = (const float*)d_in[1];
  const float* ln1_b = (const float*)d_in[2];
  const float* Wq = (const float*)d_in[3];
  const float* bq = (const float*)d_in[4];
  const float* Wk = (const float*)d_in[5];
  const float* bk = (const float*)d_in[6];
  const float* Wv = (const float*)d_in[7];
  const float* bv = (const float*)d_in[8];
  const float* Wo = (const float*)d_in[9];
  const float* bo = (const float*)d_in[10];
  const float* kg  = (const float*)d_in[11];
  const float* kbb = (const float*)d_in[12];
  const float* vg  = (const float*)d_in[13];
  const float* vbb = (const float*)d_in[14];
  const float* ln2_g = (const float*)d_in[15];
  const float* ln2_b = (const float*)d_in[16];
  const float* W1 = (const float*)d_in[17];
  const float* b1 = (const float*)d_in[18];
  const float* W2 = (const float*)d_in[19];
  const float* b2 = (const float*)d_in[20];
  float* outF = (float*)d_out;

  char* ws = (char*)d_ws;
  size_t off = 0;
  auto alloc = [&](size_t bytes) { char* p = ws + off; off += (bytes + 255) & ~(size_t)255; return p; };
  u16* bufX   = (u16*)alloc((size_t)MROWS*256*2);   // LN1 out, later x2 (fused LN2 out)
  u16* bufKV  = (u16*)alloc((size_t)MROWS*512*2);
  u16* Wkv_t  = (u16*)alloc(512*256*2);
  u16* W1_t   = (u16*)alloc(1024*256*2);
  u16* W2_t   = (u16*)alloc(256*1024*2);
  u16* Woe_t  = (u16*)alloc((size_t)8*256*256*2);
  u16* Watt   = (u16*)alloc((size_t)8*256*256*2);
  u16* wq_bf  = (u16*)alloc(256*256*2);
  float* kvb  = (float*)alloc((size_t)64*1024*4);
  float* bkv  = (float*)alloc(512*4);
  float* be   = (float*)alloc(8*256*4);
  (void)ws_size; (void)out_size; (void)n_in; (void)in_sizes;

  // prep (single launch)
  prep_kernel<<<657, 256, 0, stream>>>(Wk, Wv, W1, W2, Wq, bk, bv,
                                       Wkv_t, W1_t, W2_t, wq_bf, kvb, bkv);

  // x = LN1(fx)
  ln_kernel<<<MTOT/4, 256, 0, stream>>>(fx, ln1_g, ln1_b, bufX, MTOT);

  // KV = x @ [Wk|Wv] + [bk|bv]  (R10 bounce epilogue)
  gemm256<0><<<dim3(MT_FULL, 2, 1), 512, 0, stream>>>(
      bufX, 256, Wkv_t, 256, 0, bkv, 0, nullptr, bufKV, 512, 256, MTOT, 0,
      nullptr, nullptr, nullptr);

  // kv[b,h] = LN(k)^T LN(v) / N
  kv_kernel<<<dim3(64, 15), 256, 0, stream>>>(bufKV, kg, kbb, vg, vbb, kvb);

  // kvWo, W_att, be
  woeff_kernel<<<2048, 256, 0, stream>>>(kvb, Wo, Woe_t);
  watt_kernel<<<2048, 256, 0, stream>>>(wq_bf, Woe_t, Watt);
  be_kernel<<<8, 256, 0, stream>>>(bq, bo, Woe_t, be);

  // out = fx + x @ W_att[b] + be[b]  AND  x2 = LN2(out) (fused, EPI 3)
  gemm256<3><<<dim3(MT_BATCH, 1, 8), 512, 0, stream>>>(
      bufX, 256, Watt, 256, 65536, be, 256, fx, outF, 256, 256, NTOK, NTOK,
      ln2_g, ln2_b, bufX);

  // out += gelu(x2 @ W1 + b1) @ W2 + b2   (fused MLP v4: 72KB LDS, 2 blocks/CU)
  mlp_fused4<<<MLP_TILES, 512, 0, stream>>>(bufX, W1_t, W2_t, b1, b2, outF, MTOT);
}

// Round 15
// 293.864 us; speedup vs baseline: 1.1530x; 1.1530x over previous
//
#include <hip/hip_runtime.h>
#include <hip/hip_bf16.h>
#include <stdint.h>

#define B_ 8
#define NTOK 7225
#define MTOT (B_*NTOK)      // 57800
#define MROWS 58368         // padded rows for all M-row buffers (228*256)
#define MT_FULL 226         // ceil(57800/256)
#define MT_BATCH 29         // ceil(7225/256)
#define MLP_TILES 904       // ceil(57800/64)

typedef unsigned short u16;
typedef u16 u16x8 __attribute__((ext_vector_type(8)));
typedef u16 u16x4 __attribute__((ext_vector_type(4)));
typedef __bf16 bf16x8 __attribute__((ext_vector_type(8)));
typedef float f32x4 __attribute__((ext_vector_type(4)));

__device__ inline float bf2f(u16 u){ union{float f;uint32_t i;}c; c.i=((uint32_t)u)<<16; return c.f; }
__device__ inline u16 f2bf(float f){ union{float f;uint32_t i;}c; c.f=f; uint32_t x=c.i;
                                     return (u16)((x + 0x7fffu + ((x>>16)&1u))>>16); }
__device__ inline uint32_t cvt_pk_bf16(float a, float b){
  uint32_t r; asm("v_cvt_pk_bf16_f32 %0, %1, %2" : "=v"(r) : "v"(a), "v"(b)); return r;
}
// fast tanh-gelu: 0.5x(1+tanh t) == x * (1 - 1/(exp(2t)+1))
__device__ inline float gelu_f(float x){
  float t = 0.7978845608028654f * x * (1.0f + 0.044715f*x*x);
  float e = __expf(2.0f*t);
  return x * (1.0f - __builtin_amdgcn_rcpf(e + 1.0f));
}

__device__ inline void gload_lds16(const u16* g, u16* l) {
  __builtin_amdgcn_global_load_lds(
      (__attribute__((address_space(1))) void*)(const_cast<u16*>(g)),
      (__attribute__((address_space(3))) void*)(l), 16, 0, 0);
}

// ============ 256x256-tile GEMM (R7 schedule) + coalesced bf16 epilogue (R10) ============
// EPI 0: bf16 = acc+bias (LDS-bounce, 512B-row coalesced stores)
// EPI 3: f32 out = v = acc+bias+res AND bf16 x2 = LayerNorm_row(v)*g2+b2 (fused LN2)
template<int EPI>
__global__ __launch_bounds__(512, 2)
void gemm256(const u16* __restrict__ A, int lda,
             const u16* __restrict__ Bm, int ldb, long bStride,
             const float* __restrict__ bias, int biasStride,
             const float* __restrict__ res,
             void* __restrict__ outp, int ldo,
             int K, int rowsValid, int batchRowStride,
             const float* __restrict__ g2, const float* __restrict__ b2,
             u16* __restrict__ x2out)
{
  __shared__ alignas(16) u16 lds[65536];   // A: [0,32768), B: [32768,65536)
  const int tid = threadIdx.x;
  const int wid = tid >> 6, lane = tid & 63;
  const int wm = wid >> 2, wn = wid & 3;

  const int gx = gridDim.x, gy = gridDim.y;
  const int n = gx * gy;
  const int flat = blockIdx.y * gx + blockIdx.x;
  const int qq = n >> 3, rr = n & 7;
  const int xcd = flat & 7, pos = flat >> 3;
  const int swz = (xcd < rr ? xcd*(qq+1) : rr*(qq+1) + (xcd-rr)*qq) + pos;
  const int bx = swz / gy, by = swz % gy;
  const int bz = blockIdx.z;

  const long rowBase = (long)bz * batchRowStride + (long)bx * 256;
  const int colBase = by * 256;
  const u16* Bp = Bm + (long)bz * bStride;
  const float* biasP = bias + bz * biasStride;

  const int srow = lane >> 2;
  const int scol = ((lane & 3) ^ ((lane >> 3) & 3)) * 8;
  const int NT = K >> 6;

  auto stageHalf = [&](int bf, int kt, int sel) {
    const int sub = sel >> 1;
    const int k0 = (kt << 6) + sub*32 + scol;
    u16* base = lds + ((sel & 1) ? 32768 : 0) + (bf*2 + sub)*8192;
#pragma unroll
    for (int i = 0; i < 2; ++i) {
      const int r0 = (wid*2 + i)*16;
      if ((sel & 1) == 0)
        gload_lds16(A + (rowBase + r0 + srow)*(long)lda + k0, base + r0*32);
      else
        gload_lds16(Bp + (long)(colBase + r0 + srow)*ldb + k0, base + r0*32);
    }
  };

  f32x4 acc[8][4] = {};
  bf16x8 afr[4], bfr[4];
  const int lr = lane & 15;
  const int sl = lane >> 4;
  const int sp = (sl ^ ((lr >> 1) & 3)) * 8;

  stageHalf(0, 0, 0); stageHalf(0, 0, 1); stageHalf(0, 0, 2); stageHalf(0, 0, 3);

  for (int kt = 0; kt < NT; ++kt) {
    const int bf = kt & 1;
    const bool st = (kt + 1 < NT);
#pragma unroll
    for (int ph = 0; ph < 4; ++ph) {
      const int sub = ph >> 1, mh = ph & 1;
      if (ph == 0) {
        asm volatile("s_waitcnt vmcnt(4)" ::: "memory");
      } else if (ph == 2) {
        if (kt == NT - 1) asm volatile("s_waitcnt vmcnt(0)" ::: "memory");
        else              asm volatile("s_waitcnt vmcnt(4)" ::: "memory");
      } else {
        asm volatile("s_waitcnt vmcnt(6)" ::: "memory");
      }
      __builtin_amdgcn_s_barrier();
      const u16* Ab = lds + (bf*2 + sub)*8192;
      const u16* Bb = lds + 32768 + (bf*2 + sub)*8192;
      if (mh == 0) {
#pragma unroll
        for (int ni = 0; ni < 4; ++ni)
          bfr[ni] = *reinterpret_cast<const bf16x8*>(&Bb[(wn*64 + ni*16 + lr)*32 + sp]);
      }
#pragma unroll
      for (int i = 0; i < 4; ++i)
        afr[i] = *reinterpret_cast<const bf16x8*>(&Ab[(wm*128 + (mh*4 + i)*16 + lr)*32 + sp]);
      if (st) stageHalf(bf ^ 1, kt + 1, ph);
      asm volatile("s_waitcnt lgkmcnt(0)" ::: "memory");
      __builtin_amdgcn_sched_barrier(0);
      __builtin_amdgcn_s_setprio(1);
#pragma unroll
      for (int i = 0; i < 4; ++i)
#pragma unroll
        for (int ni = 0; ni < 4; ++ni)
          acc[mh*4 + i][ni] =
              __builtin_amdgcn_mfma_f32_16x16x32_bf16(bfr[ni], afr[i], acc[mh*4 + i][ni], 0, 0, 0);
      __builtin_amdgcn_s_setprio(0);
    }
  }

  const int cq = sl * 4;
  if (EPI <= 1) {
    __syncthreads();
#pragma unroll
    for (int mi = 0; mi < 8; ++mi) {
      const int r = wm*128 + mi*16 + lr;
#pragma unroll
      for (int ni = 0; ni < 4; ++ni) {
        const int c = wn*64 + ni*16 + cq;
        f32x4 v = acc[mi][ni] + *reinterpret_cast<const f32x4*>(&biasP[colBase + c]);
        uint2 pk;
        if (EPI == 1) { pk.x = cvt_pk_bf16(gelu_f(v[0]), gelu_f(v[1]));
                        pk.y = cvt_pk_bf16(gelu_f(v[2]), gelu_f(v[3])); }
        else          { pk.x = cvt_pk_bf16(v[0], v[1]); pk.y = cvt_pk_bf16(v[2], v[3]); }
        const int unit = ((c >> 3) ^ (r & 7));
        *reinterpret_cast<uint2*>(lds + r*256 + unit*8 + (c & 7)) = pk;
      }
    }
    __syncthreads();
#pragma unroll
    for (int p = 0; p < 16; ++p) {
      const int idx = p*512 + tid;
      const int r = idx >> 5, u = idx & 31;
      const int phys = u ^ (r & 7);
      u16x8 val = *reinterpret_cast<const u16x8*>(lds + r*256 + phys*8);
      *reinterpret_cast<u16x8*>((u16*)outp + (rowBase + r)*(long)ldo + colBase + u*8) = val;
    }
  } else {
    // EPI 3: v = acc + be + fx; out=v (f32); x2 = LN_row(v)*g2+b2 (bf16). colBase==0, ldo==256.
    float* red = reinterpret_cast<float*>(lds);
    __syncthreads();
#pragma unroll
    for (int mi = 0; mi < 8; ++mi) {
      const int r = wm*128 + mi*16 + lr;
      const bool valid = (bx*256 + r < rowsValid);
      const long grow = rowBase + r;
      float s_r = 0.f, q_r = 0.f;
#pragma unroll
      for (int ni = 0; ni < 4; ++ni) {
        const int c0 = wn*64 + ni*16 + cq;
        f32x4 rv = valid ? *reinterpret_cast<const f32x4*>((const float*)res + grow*256 + c0)
                         : f32x4{0.f,0.f,0.f,0.f};
        f32x4 v = acc[mi][ni] + *reinterpret_cast<const f32x4*>(&biasP[c0]) + rv;
        acc[mi][ni] = v;
        s_r += v[0]+v[1]+v[2]+v[3];
        q_r += v[0]*v[0]+v[1]*v[1]+v[2]*v[2]+v[3]*v[3];
      }
      s_r += __shfl_xor(s_r, 16); s_r += __shfl_xor(s_r, 32);
      q_r += __shfl_xor(q_r, 16); q_r += __shfl_xor(q_r, 32);
      if (sl == 0) {
        red[       (wm*4 + wn)*128 + mi*16 + lr] = s_r;
        red[1024 + (wm*4 + wn)*128 + mi*16 + lr] = q_r;
      }
    }
    __syncthreads();
#pragma unroll
    for (int mi = 0; mi < 8; ++mi) {
      const int r = wm*128 + mi*16 + lr;
      if (bx*256 + r >= rowsValid) continue;
      const long grow = rowBase + r;
      const int rb = wm*4*128 + mi*16 + lr;
      float s_t = red[rb] + red[rb+128] + red[rb+256] + red[rb+384];
      float q_t = red[1024+rb] + red[1024+rb+128] + red[1024+rb+256] + red[1024+rb+384];
      const float m = s_t * (1.0f/256.0f);
      const float var = q_t * (1.0f/256.0f) - m*m;
      const float rs = rsqrtf(var + 1e-5f);
#pragma unroll
      for (int ni = 0; ni < 4; ++ni) {
        const int c0 = wn*64 + ni*16 + cq;
        const long oidx = grow*256 + c0;
        f32x4 v = acc[mi][ni];
        *reinterpret_cast<f32x4*>((float*)outp + oidx) = v;
        f32x4 gv = *reinterpret_cast<const f32x4*>(&g2[c0]);
        f32x4 bv = *reinterpret_cast<const f32x4*>(&b2[c0]);
        f32x4 xn = (v - m) * rs * gv + bv;
        uint2 pk; pk.x = cvt_pk_bf16(xn[0], xn[1]); pk.y = cvt_pk_bf16(xn[2], xn[3]);
        *reinterpret_cast<uint2*>(x2out + oidx) = pk;
      }
    }
  }
}

// ============ fused MLP v4b: v2's serial schedule at TRUE 2 blocks/CU (72KB LDS) ============
// out += gelu(x2@W1+b1)@W2 + b2.  M-tile 64, 512 thr = 8 waves (2M x 4N), chunk = 64 H-cols
// (16 chunks). LDS: Xs 32K + Wbuf 32K (16384 u16 — R14's bug was 32768 u16 = 64K -> 104K
// total -> 1 block/CU) + Hs 8K = 72K -> 2 blocks/CU. Serial vmcnt(0) weight-stage drains
// overlap the co-resident block's MFMA phases (m114 TLP).
__global__ __launch_bounds__(512, 4)
void mlp_fused4(const u16* __restrict__ x2, const u16* __restrict__ W1t,
                const u16* __restrict__ W2t, const float* __restrict__ b1,
                const float* __restrict__ b2, float* __restrict__ outF,
                int rowsValid)
{
  __shared__ alignas(16) u16 Xs[64*256];   // 32K: [64 r][32 u], phys = u ^ (r&31)
  __shared__ alignas(16) u16 Wb[16384];    // 32K: W1c [64 hcol][32 u] or W2c [256 ocol][8 u]
  __shared__ alignas(16) u16 Hs[64*64];    //  8K: [64 r][8 u], phys = u ^ (r&7)
  const int tid = threadIdx.x;
  const int wid = tid >> 6, lane = tid & 63;
  const int wm = wid >> 2, wn = wid & 3;   // 2M x 4N
  const int lr = lane & 15, sl = lane >> 4;
  const long rowBase = (long)blockIdx.x * 64;

  // ---- staging (all coalesced; dest linear in unit id, global col pre-swizzled, G21)
#pragma unroll
  for (int i = 0; i < 4; ++i) {            // Xs: 2048 units
    const int u = i*512 + tid;
    const int r = u >> 5, pu = u & 31;
    gload_lds16(x2 + (rowBase + r)*256 + ((pu ^ (r & 31)) << 3), &Xs[u*8]);
  }
  auto stageW1 = [&](int c) {              // [64 hcol][256 k] = 32KB
#pragma unroll
    for (int i = 0; i < 4; ++i) {
      const int u = i*512 + tid;
      const int r = u >> 5, pu = u & 31;
      gload_lds16(W1t + (long)(c*64 + r)*256 + ((pu ^ (r & 31)) << 3), &Wb[u*8]);
    }
  };
  auto stageW2 = [&](int c) {              // [256 ocol][64 k] = 32KB
#pragma unroll
    for (int i = 0; i < 4; ++i) {
      const int u = i*512 + tid;
      const int r = u >> 3, pu = u & 7;
      gload_lds16(W2t + (long)r*1024 + c*64 + ((pu ^ (r & 7)) << 3), &Wb[u*8]);
    }
  };
  stageW1(0);
  asm volatile("s_waitcnt vmcnt(0)" ::: "memory");
  __syncthreads();

  f32x4 acc2[2][4] = {};
  for (int c = 0; c < 16; ++c) {
    // ---- gemm1: acc1[mi] = Xs rows (wm*32+mi*16) @ W1c^T (K=256); wave-n = 16 hcols
    f32x4 acc1[2] = {};
#pragma unroll
    for (int kk = 0; kk < 8; ++kk) {
      const int u = kk*4 + sl;
      const int rB = wn*16 + lr;
      bf16x8 wb = *reinterpret_cast<const bf16x8*>(&Wb[(rB*32 + (u ^ (rB & 31)))*8]);
#pragma unroll
      for (int mi = 0; mi < 2; ++mi) {
        const int rA = wm*32 + mi*16 + lr;
        bf16x8 xa = *reinterpret_cast<const bf16x8*>(&Xs[(rA*32 + (u ^ (rA & 31)))*8]);
        acc1[mi] = __builtin_amdgcn_mfma_f32_16x16x32_bf16(wb, xa, acc1[mi], 0, 0, 0);
      }
    }
    // ---- gelu + b1 -> Hs (row = rA, chunk-local col = wn*16 + sl*4)
    const float* b1c = b1 + c*64;
#pragma unroll
    for (int mi = 0; mi < 2; ++mi) {
      const int r = wm*32 + mi*16 + lr;
      const int col = wn*16 + sl*4;
      f32x4 v = acc1[mi] + *reinterpret_cast<const f32x4*>(&b1c[col]);
      uint2 pk; pk.x = cvt_pk_bf16(gelu_f(v[0]), gelu_f(v[1]));
      pk.y = cvt_pk_bf16(gelu_f(v[2]), gelu_f(v[3]));
      const int uw = (col >> 3) ^ (r & 7);
      *reinterpret_cast<uint2*>(&Hs[r*64 + uw*8 + (col & 7)]) = pk;
    }
    asm volatile("s_waitcnt lgkmcnt(0)" ::: "memory");
    __builtin_amdgcn_s_barrier();          // Wbuf free (gemm1 reads done) + Hs published
    stageW2(c);
    asm volatile("s_waitcnt vmcnt(0)" ::: "memory");
    __builtin_amdgcn_s_barrier();          // W2c visible to all waves

    // ---- gemm2: acc2[mi][nj] += Hs @ W2c^T (K=64); wave-n = 64 ocols
#pragma unroll
    for (int kk2 = 0; kk2 < 2; ++kk2) {
      const int u = kk2*4 + sl;
      bf16x8 ha[2];
#pragma unroll
      for (int mi = 0; mi < 2; ++mi) {
        const int r = wm*32 + mi*16 + lr;
        ha[mi] = *reinterpret_cast<const bf16x8*>(&Hs[(r*8 + (u ^ (r & 7)))*8]);
      }
#pragma unroll
      for (int nj = 0; nj < 4; ++nj) {
        const int rB = wn*64 + nj*16 + lr;
        bf16x8 wb = *reinterpret_cast<const bf16x8*>(&Wb[(rB*8 + (u ^ (rB & 7)))*8]);
#pragma unroll
        for (int mi = 0; mi < 2; ++mi)
          acc2[mi][nj] = __builtin_amdgcn_mfma_f32_16x16x32_bf16(wb, ha[mi], acc2[mi][nj], 0, 0, 0);
      }
    }
    __builtin_amdgcn_s_barrier();          // Wbuf free (gemm2 reads done)
    if (c + 1 < 16) {
      stageW1(c + 1);
      asm volatile("s_waitcnt vmcnt(0)" ::: "memory");
      __builtin_amdgcn_s_barrier();        // W1(c+1) visible
    }
  }
  // ---- epilogue: out += acc2 + b2 (f32 RMW, 16B/lane, row-guarded)
#pragma unroll
  for (int mi = 0; mi < 2; ++mi) {
    const int r = wm*32 + mi*16 + lr;
    if (rowBase + r < rowsValid) {
      float* orow = outF + (rowBase + r)*256;
#pragma unroll
      for (int nj = 0; nj < 4; ++nj) {
        const int col = wn*64 + nj*16 + sl*4;
        f32x4 v = acc2[mi][nj] + *reinterpret_cast<const f32x4*>(&b2[col])
                + *reinterpret_cast<const f32x4*>(&orow[col]);
        *reinterpret_cast<f32x4*>(&orow[col]) = v;
      }
    }
  }
}

// ---------------- LayerNorm over C=256, one wave per token, bf16 out ----------------
__global__ __launch_bounds__(256)
void ln_kernel(const float* __restrict__ in, const float* __restrict__ g,
               const float* __restrict__ bt, u16* __restrict__ out, int M)
{
  const int wv = threadIdx.x >> 6, lane = threadIdx.x & 63;
  const int t = blockIdx.x * 4 + wv;
  if (t >= M) return;
  const float4 x = reinterpret_cast<const float4*>(in + (long)t*256)[lane];
  float s = x.x + x.y + x.z + x.w;
  float q = x.x*x.x + x.y*x.y + x.z*x.z + x.w*x.w;
#pragma unroll
  for (int o = 32; o > 0; o >>= 1) { s += __shfl_xor(s, o); q += __shfl_xor(q, o); }
  const float m  = s * (1.0f/256.0f);
  const float var = q * (1.0f/256.0f) - m*m;
  const float rs = rsqrtf(var + 1e-5f);
  const float4 gv = reinterpret_cast<const float4*>(g)[lane];
  const float4 bv = reinterpret_cast<const float4*>(bt)[lane];
  uint2 o4;
  o4.x = cvt_pk_bf16((x.x - m)*rs*gv.x + bv.x, (x.y - m)*rs*gv.y + bv.y);
  o4.y = cvt_pk_bf16((x.z - m)*rs*gv.z + bv.z, (x.w - m)*rs*gv.w + bv.w);
  *reinterpret_cast<uint2*>(out + (long)t*256 + lane*4) = o4;
}

// -------- fused per-head LN(k), LN(v) + kv[b,h] += k^T v / N (atomic f32) --------
__global__ __launch_bounds__(256)
void kv_kernel(const u16* __restrict__ KV,
               const float* __restrict__ kg, const float* __restrict__ kb,
               const float* __restrict__ vg, const float* __restrict__ vb,
               float* __restrict__ kvout)
{
  const int bh = blockIdx.x, b = bh >> 3, h = bh & 7;
  const int tid = threadIdx.x;
  __shared__ u16 kls[256][32];
  __shared__ u16 vls[256][32];
  __shared__ float sg[4][32];
  if (tid < 32) {
    sg[0][tid] = kg[h*32 + tid];
    sg[1][tid] = kb[h*32 + tid];
    sg[2][tid] = vg[h*32 + tid];
    sg[3][tid] = vb[h*32 + tid];
  }
  const int d = tid >> 3, e0 = (tid & 7) * 4;
  float a0=0, a1=0, a2=0, a3=0;

  for (int sub = 0; sub < 2; ++sub) {
    const int r = blockIdx.y * 512 + sub * 256 + tid;
    __syncthreads();
    if (r < NTOK) {
      const u16* rowp = KV + (long)(b*NTOK + r)*512;
#pragma unroll
      for (int kv2 = 0; kv2 < 2; ++kv2) {
        const u16* p = rowp + (kv2 ? 256 : 0) + h*32;
        float xv[32]; float s = 0.f;
#pragma unroll
        for (int q4 = 0; q4 < 4; ++q4) {
          u16x8 u = *reinterpret_cast<const u16x8*>(p + q4*8);
#pragma unroll
          for (int j = 0; j < 8; ++j) { float f = bf2f(u[j]); xv[q4*8+j] = f; s += f; }
        }
        const float m = s * (1.0f/32.0f);
        float vv = 0.f;
#pragma unroll
        for (int j = 0; j < 32; ++j) { float d2 = xv[j]-m; vv += d2*d2; }
        const float rs = rsqrtf(vv*(1.0f/32.0f) + 1e-5f);
        const float* gg = sg[kv2 ? 2 : 0];
        const float* bb = sg[kv2 ? 3 : 1];
        u16 (*dst)[32] = kv2 ? vls : kls;
#pragma unroll
        for (int j = 0; j < 32; ++j) dst[tid][j] = f2bf((xv[j]-m)*rs*gg[j] + bb[j]);
      }
    } else {
#pragma unroll
      for (int j = 0; j < 32; ++j) { kls[tid][j] = 0; vls[tid][j] = 0; }
    }
    __syncthreads();
#pragma unroll 4
    for (int rr = 0; rr < 256; ++rr) {
      const float kd = bf2f(kls[rr][d]);
      u16x4 v4 = *reinterpret_cast<const u16x4*>(&vls[rr][e0]);
      a0 += kd * bf2f(v4[0]); a1 += kd * bf2f(v4[1]);
      a2 += kd * bf2f(v4[2]); a3 += kd * bf2f(v4[3]);
    }
  }
  const float sc = 1.0f / (float)NTOK;
  float* o = kvout + (long)bh*1024 + d*32 + e0;
  atomicAdd(o+0, a0*sc); atomicAdd(o+1, a1*sc);
  atomicAdd(o+2, a2*sc); atomicAdd(o+3, a3*sc);
}

// -------- Woe_t[b][c][j=h*32+d] = sum_e kv[b,h,d,e] * Wo[h*32+e][c] --------
__global__ __launch_bounds__(256)
void woeff_kernel(const float* __restrict__ kv, const float* __restrict__ Wo,
                  u16* __restrict__ Woet)
{
  const int b = blockIdx.x >> 8, c = blockIdx.x & 255;
  const int rtid = threadIdx.x;
  const int h = rtid >> 5, dd = rtid & 31;
  const float* kvp = kv + ((long)(b*8 + h)*32 + dd)*32;
  float s = 0.f;
#pragma unroll 8
  for (int e = 0; e < 32; ++e) s += kvp[e] * Wo[(h*32 + e)*256 + c];
  Woet[(long)(b*256 + c)*256 + rtid] = f2bf(s);
}

// -------- Watt[b][c][k] = sum_j Wq[k,j] * kvWo[b][j,c] --------
__global__ __launch_bounds__(256)
void watt_kernel(const u16* __restrict__ wq_bf, const u16* __restrict__ Woet,
                 u16* __restrict__ Watt)
{
  const int b = blockIdx.x >> 8, c = blockIdx.x & 255;
  const int k = threadIdx.x;
  const u16* wr = wq_bf + (long)k*256;
  const u16* er = Woet + ((long)(b*256 + c))*256;
  float s = 0.f;
#pragma unroll 4
  for (int j0 = 0; j0 < 256; j0 += 8) {
    u16x8 wv = *reinterpret_cast<const u16x8*>(wr + j0);
    u16x8 ev = *reinterpret_cast<const u16x8*>(er + j0);
#pragma unroll
    for (int j = 0; j < 8; ++j) s += bf2f(wv[j]) * bf2f(ev[j]);
  }
  Watt[((long)(b*256 + c))*256 + k] = f2bf(s);
}

// -------- be[b][c] = sum_j bq[j] * kvWo[b][j,c] + bo[c] --------
__global__ __launch_bounds__(256)
void be_kernel(const float* __restrict__ bq, const float* __restrict__ bo,
               const u16* __restrict__ Woet, float* __restrict__ be)
{
  const int b = blockIdx.x, c = threadIdx.x;
  const u16* er = Woet + ((long)(b*256 + c))*256;
  float s = bo[c];
#pragma unroll 4
  for (int j0 = 0; j0 < 256; j0 += 8) {
    u16x8 ev = *reinterpret_cast<const u16x8*>(er + j0);
#pragma unroll
    for (int j = 0; j < 8; ++j) s += bq[j0+j] * bf2f(ev[j]);
  }
  be[b*256 + c] = s;
}

// ---------------- mega-prep ----------------
__device__ void transpose_tile(const float* __restrict__ src, u16* __restrict__ dst,
                               int R, int C, int tcx, int trY)
{
  __shared__ float t[32][33];
  const int tc = tcx * 32, tr = trY * 32;
  const int lx = threadIdx.x & 31, ly = threadIdx.x >> 5;
#pragma unroll
  for (int i = 0; i < 32; i += 8)
    t[ly + i][lx] = src[(long)(tr + ly + i)*C + tc + lx];
  __syncthreads();
#pragma unroll
  for (int i = 0; i < 32; i += 8)
    dst[(long)(tc + ly + i)*R + tr + lx] = f2bf(t[lx][ly + i]);
}

__global__ __launch_bounds__(256)
void prep_kernel(const float* __restrict__ Wk, const float* __restrict__ Wv,
                 const float* __restrict__ W1, const float* __restrict__ W2,
                 const float* __restrict__ Wq,
                 const float* __restrict__ bk, const float* __restrict__ bv,
                 u16* __restrict__ Wkv_t, u16* __restrict__ W1_t, u16* __restrict__ W2_t,
                 u16* __restrict__ wq_bf, float* __restrict__ kvb, float* __restrict__ bkv)
{
  int b = blockIdx.x;
  if (b < 256)      { transpose_tile(W1, W1_t, 256, 1024, b & 31, b >> 5); }
  else if (b < 512) { b -= 256; transpose_tile(W2, W2_t, 1024, 256, b & 7, b >> 3); }
  else if (b < 576) { b -= 512; transpose_tile(Wk, Wkv_t,         256, 256, b & 7, b >> 3); }
  else if (b < 640) { b -= 576; transpose_tile(Wv, Wkv_t + 65536, 256, 256, b & 7, b >> 3); }
  else if (b < 648) {
    const int base = (b - 640) * 8192 + threadIdx.x;
#pragma unroll
    for (int i = 0; i < 32; ++i) wq_bf[base + i*256] = f2bf(Wq[base + i*256]);
  } else if (b < 656) {
    const int base = (b - 648) * 8192 + threadIdx.x;
#pragma unroll
    for (int i = 0; i < 32; ++i) kvb[base + i*256] = 0.f;
  } else {
    const int i = threadIdx.x;
    bkv[i] = bk[i]; bkv[256 + i] = bv[i];
  }
}

// ---------------- launch ----------------
extern "C" void kernel_launch(void* const* d_in, const int* in_sizes, int n_in,
                              void* d_out, int out_size, void* d_ws, size_t ws_size,
                              hipStream_t stream)
{
  const float* fx    = (const float*)d_in[0];
  const float* ln1_g = (const float*)d_in[1];
  const float* ln1_b = (const float*)d_in[2];
  const float* Wq = (const float*)d_in[3];
  const float* bq = (const float*)d_in[4];
  const float* Wk = (const float*)d_in[5];
  const float* bk = (const float*)d_in[6];
  const float* Wv = (const float*)d_in[7];
  const float* bv = (const float*)d_in[8];
  const float* Wo = (const float*)d_in[9];
  const float* bo = (const float*)d_in[10];
  const float* kg  = (const float*)d_in[11];
  const float* kbb = (const float*)d_in[12];
  const float* vg  = (const float*)d_in[13];
  const float* vbb = (const float*)d_in[14];
  const float* ln2_g = (const float*)d_in[15];
  const float* ln2_b = (const float*)d_in[16];
  const float* W1 = (const float*)d_in[17];
  const float* b1 = (const float*)d_in[18];
  const float* W2 = (const float*)d_in[19];
  const float* b2 = (const float*)d_in[20];
  float* outF = (float*)d_out;

  char* ws = (char*)d_ws;
  size_t off = 0;
  auto alloc = [&](size_t bytes) { char* p = ws + off; off += (bytes + 255) & ~(size_t)255; return p; };
  u16* bufX   = (u16*)alloc((size_t)MROWS*256*2);   // LN1 out, later x2 (fused LN2 out)
  u16* bufKV  = (u16*)alloc((size_t)MROWS*512*2);
  u16* Wkv_t  = (u16*)alloc(512*256*2);
  u16* W1_t   = (u16*)alloc(1024*256*2);
  u16* W2_t   = (u16*)alloc(256*1024*2);
  u16* Woe_t  = (u16*)alloc((size_t)8*256*256*2);
  u16* Watt   = (u16*)alloc((size_t)8*256*256*2);
  u16* wq_bf  = (u16*)alloc(256*256*2);
  float* kvb  = (float*)alloc((size_t)64*1024*4);
  float* bkv  = (float*)alloc(512*4);
  float* be   = (float*)alloc(8*256*4);
  (void)ws_size; (void)out_size; (void)n_in; (void)in_sizes;

  // prep (single launch)
  prep_kernel<<<657, 256, 0, stream>>>(Wk, Wv, W1, W2, Wq, bk, bv,
                                       Wkv_t, W1_t, W2_t, wq_bf, kvb, bkv);

  // x = LN1(fx)
  ln_kernel<<<MTOT/4, 256, 0, stream>>>(fx, ln1_g, ln1_b, bufX, MTOT);

  // KV = x @ [Wk|Wv] + [bk|bv]  (R10 bounce epilogue)
  gemm256<0><<<dim3(MT_FULL, 2, 1), 512, 0, stream>>>(
      bufX, 256, Wkv_t, 256, 0, bkv, 0, nullptr, bufKV, 512, 256, MTOT, 0,
      nullptr, nullptr, nullptr);

  // kv[b,h] = LN(k)^T LN(v) / N
  kv_kernel<<<dim3(64, 15), 256, 0, stream>>>(bufKV, kg, kbb, vg, vbb, kvb);

  // kvWo, W_att, be
  woeff_kernel<<<2048, 256, 0, stream>>>(kvb, Wo, Woe_t);
  watt_kernel<<<2048, 256, 0, stream>>>(wq_bf, Woe_t, Watt);
  be_kernel<<<8, 256, 0, stream>>>(bq, bo, Woe_t, be);

  // out = fx + x @ W_att[b] + be[b]  AND  x2 = LN2(out) (fused, EPI 3)
  gemm256<3><<<dim3(MT_BATCH, 1, 8), 512, 0, stream>>>(
      bufX, 256, Watt, 256, 65536, be, 256, fx, outF, 256, 256, NTOK, NTOK,
      ln2_g, ln2_b, bufX);

  // out += gelu(x2 @ W1 + b1) @ W2 + b2   (fused MLP v4b: true 72KB LDS, 2 blocks/CU)
  mlp_fused4<<<MLP_TILES, 512, 0, stream>>>(bufX, W1_t, W2_t, b1, b2, outF, MTOT);
}

// Round 17
// 293.719 us; speedup vs baseline: 1.1536x; 1.0005x over previous
//
#include <hip/hip_runtime.h>
#include <hip/hip_bf16.h>
#include <stdint.h>

#define B_ 8
#define NTOK 7225
#define MTOT (B_*NTOK)      // 57800
#define MROWS 58368         // padded rows for all M-row buffers (228*256)
#define MT_FULL 226         // ceil(57800/256)
#define MT_BATCH 29         // ceil(7225/256)
#define MLP_TILES 904       // ceil(57800/64)

typedef unsigned short u16;
typedef u16 u16x8 __attribute__((ext_vector_type(8)));
typedef u16 u16x4 __attribute__((ext_vector_type(4)));
typedef __bf16 bf16x8 __attribute__((ext_vector_type(8)));
typedef float f32x4 __attribute__((ext_vector_type(4)));

__device__ inline float bf2f(u16 u){ union{float f;uint32_t i;}c; c.i=((uint32_t)u)<<16; return c.f; }
__device__ inline u16 f2bf(float f){ union{float f;uint32_t i;}c; c.f=f; uint32_t x=c.i;
                                     return (u16)((x + 0x7fffu + ((x>>16)&1u))>>16); }
__device__ inline uint32_t cvt_pk_bf16(float a, float b){
  uint32_t r; asm("v_cvt_pk_bf16_f32 %0, %1, %2" : "=v"(r) : "v"(a), "v"(b)); return r;
}
// fast tanh-gelu: 0.5x(1+tanh t) == x * (1 - 1/(exp(2t)+1))
__device__ inline float gelu_f(float x){
  float t = 0.7978845608028654f * x * (1.0f + 0.044715f*x*x);
  float e = __expf(2.0f*t);
  return x * (1.0f - __builtin_amdgcn_rcpf(e + 1.0f));
}

__device__ inline void gload_lds16(const u16* g, u16* l) {
  __builtin_amdgcn_global_load_lds(
      (__attribute__((address_space(1))) void*)(const_cast<u16*>(g)),
      (__attribute__((address_space(3))) void*)(l), 16, 0, 0);
}

// ============ 256x256-tile GEMM (R7 schedule) — EPI 3 (att + fused LN2), R15-exact ======
template<int EPI>
__global__ __launch_bounds__(512, 2)
void gemm256(const u16* __restrict__ A, int lda,
             const u16* __restrict__ Bm, int ldb, long bStride,
             const float* __restrict__ bias, int biasStride,
             const float* __restrict__ res,
             void* __restrict__ outp, int ldo,
             int K, int rowsValid, int batchRowStride,
             const float* __restrict__ g2, const float* __restrict__ b2,
             u16* __restrict__ x2out)
{
  __shared__ alignas(16) u16 lds[65536];   // A: [0,32768), B: [32768,65536)
  const int tid = threadIdx.x;
  const int wid = tid >> 6, lane = tid & 63;
  const int wm = wid >> 2, wn = wid & 3;

  const int gx = gridDim.x, gy = gridDim.y;
  const int n = gx * gy;
  const int flat = blockIdx.y * gx + blockIdx.x;
  const int qq = n >> 3, rr = n & 7;
  const int xcd = flat & 7, pos = flat >> 3;
  const int swz = (xcd < rr ? xcd*(qq+1) : rr*(qq+1) + (xcd-rr)*qq) + pos;
  const int bx = swz / gy, by = swz % gy;
  const int bz = blockIdx.z;

  const long rowBase = (long)bz * batchRowStride + (long)bx * 256;
  const int colBase = by * 256;
  const u16* Bp = Bm + (long)bz * bStride;
  const float* biasP = bias + bz * biasStride;

  const int srow = lane >> 2;
  const int scol = ((lane & 3) ^ ((lane >> 3) & 3)) * 8;
  const int NT = K >> 6;

  auto stageHalf = [&](int bf, int kt, int sel) {
    const int sub = sel >> 1;
    const int k0 = (kt << 6) + sub*32 + scol;
    u16* base = lds + ((sel & 1) ? 32768 : 0) + (bf*2 + sub)*8192;
#pragma unroll
    for (int i = 0; i < 2; ++i) {
      const int r0 = (wid*2 + i)*16;
      if ((sel & 1) == 0)
        gload_lds16(A + (rowBase + r0 + srow)*(long)lda + k0, base + r0*32);
      else
        gload_lds16(Bp + (long)(colBase + r0 + srow)*ldb + k0, base + r0*32);
    }
  };

  f32x4 acc[8][4] = {};
  bf16x8 afr[4], bfr[4];
  const int lr = lane & 15;
  const int sl = lane >> 4;
  const int sp = (sl ^ ((lr >> 1) & 3)) * 8;

  stageHalf(0, 0, 0); stageHalf(0, 0, 1); stageHalf(0, 0, 2); stageHalf(0, 0, 3);

  for (int kt = 0; kt < NT; ++kt) {
    const int bf = kt & 1;
    const bool st = (kt + 1 < NT);
#pragma unroll
    for (int ph = 0; ph < 4; ++ph) {
      const int sub = ph >> 1, mh = ph & 1;
      if (ph == 0) {
        asm volatile("s_waitcnt vmcnt(4)" ::: "memory");
      } else if (ph == 2) {
        if (kt == NT - 1) asm volatile("s_waitcnt vmcnt(0)" ::: "memory");
        else              asm volatile("s_waitcnt vmcnt(4)" ::: "memory");
      } else {
        asm volatile("s_waitcnt vmcnt(6)" ::: "memory");
      }
      __builtin_amdgcn_s_barrier();
      const u16* Ab = lds + (bf*2 + sub)*8192;
      const u16* Bb = lds + 32768 + (bf*2 + sub)*8192;
      if (mh == 0) {
#pragma unroll
        for (int ni = 0; ni < 4; ++ni)
          bfr[ni] = *reinterpret_cast<const bf16x8*>(&Bb[(wn*64 + ni*16 + lr)*32 + sp]);
      }
#pragma unroll
      for (int i = 0; i < 4; ++i)
        afr[i] = *reinterpret_cast<const bf16x8*>(&Ab[(wm*128 + (mh*4 + i)*16 + lr)*32 + sp]);
      if (st) stageHalf(bf ^ 1, kt + 1, ph);
      asm volatile("s_waitcnt lgkmcnt(0)" ::: "memory");
      __builtin_amdgcn_sched_barrier(0);
      __builtin_amdgcn_s_setprio(1);
#pragma unroll
      for (int i = 0; i < 4; ++i)
#pragma unroll
        for (int ni = 0; ni < 4; ++ni)
          acc[mh*4 + i][ni] =
              __builtin_amdgcn_mfma_f32_16x16x32_bf16(bfr[ni], afr[i], acc[mh*4 + i][ni], 0, 0, 0);
      __builtin_amdgcn_s_setprio(0);
    }
  }

  const int cq = sl * 4;
  {
    // EPI 3: v = acc + be + fx; out=v (f32); x2 = LN_row(v)*g2+b2 (bf16). colBase==0, ldo==256.
    float* red = reinterpret_cast<float*>(lds);
    __syncthreads();
#pragma unroll
    for (int mi = 0; mi < 8; ++mi) {
      const int r = wm*128 + mi*16 + lr;
      const bool valid = (bx*256 + r < rowsValid);
      const long grow = rowBase + r;
      float s_r = 0.f, q_r = 0.f;
#pragma unroll
      for (int ni = 0; ni < 4; ++ni) {
        const int c0 = wn*64 + ni*16 + cq;
        f32x4 rv = valid ? *reinterpret_cast<const f32x4*>((const float*)res + grow*256 + c0)
                         : f32x4{0.f,0.f,0.f,0.f};
        f32x4 v = acc[mi][ni] + *reinterpret_cast<const f32x4*>(&biasP[c0]) + rv;
        acc[mi][ni] = v;
        s_r += v[0]+v[1]+v[2]+v[3];
        q_r += v[0]*v[0]+v[1]*v[1]+v[2]*v[2]+v[3]*v[3];
      }
      s_r += __shfl_xor(s_r, 16); s_r += __shfl_xor(s_r, 32);
      q_r += __shfl_xor(q_r, 16); q_r += __shfl_xor(q_r, 32);
      if (sl == 0) {
        red[       (wm*4 + wn)*128 + mi*16 + lr] = s_r;
        red[1024 + (wm*4 + wn)*128 + mi*16 + lr] = q_r;
      }
    }
    __syncthreads();
#pragma unroll
    for (int mi = 0; mi < 8; ++mi) {
      const int r = wm*128 + mi*16 + lr;
      if (bx*256 + r >= rowsValid) continue;
      const long grow = rowBase + r;
      const int rb = wm*4*128 + mi*16 + lr;
      float s_t = red[rb] + red[rb+128] + red[rb+256] + red[rb+384];
      float q_t = red[1024+rb] + red[1024+rb+128] + red[1024+rb+256] + red[1024+rb+384];
      const float m = s_t * (1.0f/256.0f);
      const float var = q_t * (1.0f/256.0f) - m*m;
      const float rs = rsqrtf(var + 1e-5f);
#pragma unroll
      for (int ni = 0; ni < 4; ++ni) {
        const int c0 = wn*64 + ni*16 + cq;
        const long oidx = grow*256 + c0;
        f32x4 v = acc[mi][ni];
        *reinterpret_cast<f32x4*>((float*)outp + oidx) = v;
        f32x4 gv = *reinterpret_cast<const f32x4*>(&g2[c0]);
        f32x4 bv = *reinterpret_cast<const f32x4*>(&b2[c0]);
        f32x4 xn = (v - m) * rs * gv + bv;
        uint2 pk; pk.x = cvt_pk_bf16(xn[0], xn[1]); pk.y = cvt_pk_bf16(xn[2], xn[3]);
        *reinterpret_cast<uint2*>(x2out + oidx) = pk;
      }
    }
  }
}

// ============ proj64 (UNDER TEST): KV = x @ Wkv^T + bkv, weight-streamed ============
// M-tile 64, 512 thr = 8 waves (2M x 4N). 8 chunks of 64 ncols. LDS: Xs 32K + Wb 32K +
// bounce Bb 8K = 72K -> 2 blocks/CU.
__global__ __launch_bounds__(512, 4)
void proj64(const u16* __restrict__ x2, const u16* __restrict__ Wt,
            const float* __restrict__ bias, u16* __restrict__ outp)
{
  __shared__ alignas(16) u16 Xs[16384];   // 32K: [64 r][32 u], phys = u ^ (r&31)
  __shared__ alignas(16) u16 Wb[16384];   // 32K: [64 ncol][32 u], phys = u ^ (r&31)
  __shared__ alignas(16) u16 Bb[4096];    //  8K: [64 r][8 u],  phys = u ^ (r&7)
  const int tid = threadIdx.x;
  const int wid = tid >> 6, lane = tid & 63;
  const int wm = wid >> 2, wn = wid & 3;  // 2M x 4N
  const int lr = lane & 15, sl = lane >> 4;
  const long rowBase = (long)blockIdx.x * 64;

#pragma unroll
  for (int i = 0; i < 4; ++i) {           // Xs: 2048 units
    const int u = i*512 + tid;
    const int r = u >> 5, pu = u & 31;
    gload_lds16(x2 + (rowBase + r)*256 + ((pu ^ (r & 31)) << 3), &Xs[u*8]);
  }
  auto stageW = [&](int c) {              // [64 ncol][256 k] = 32KB
#pragma unroll
    for (int i = 0; i < 4; ++i) {
      const int u = i*512 + tid;
      const int r = u >> 5, pu = u & 31;
      gload_lds16(Wt + (long)(c*64 + r)*256 + ((pu ^ (r & 31)) << 3), &Wb[u*8]);
    }
  };

  for (int c = 0; c < 8; ++c) {
    stageW(c);
    asm volatile("s_waitcnt vmcnt(0)" ::: "memory");
    __builtin_amdgcn_s_barrier();         // Xs (c=0) + W(c) visible; prev copy-out done
    f32x4 acc[2] = {};
#pragma unroll
    for (int kk = 0; kk < 8; ++kk) {
      const int u = kk*4 + sl;
      const int rB = wn*16 + lr;          // ncol 0..63
      bf16x8 wb = *reinterpret_cast<const bf16x8*>(&Wb[(rB*32 + (u ^ (rB & 31)))*8]);
#pragma unroll
      for (int mi = 0; mi < 2; ++mi) {
        const int rA = wm*32 + mi*16 + lr;
        bf16x8 xa = *reinterpret_cast<const bf16x8*>(&Xs[(rA*32 + (u ^ (rA & 31)))*8]);
        acc[mi] = __builtin_amdgcn_mfma_f32_16x16x32_bf16(wb, xa, acc[mi], 0, 0, 0);
      }
    }
#pragma unroll
    for (int mi = 0; mi < 2; ++mi) {
      const int r = wm*32 + mi*16 + lr;
      const int col = wn*16 + sl*4;       // 0..63
      f32x4 v = acc[mi] + *reinterpret_cast<const f32x4*>(&bias[c*64 + col]);
      uint2 pk; pk.x = cvt_pk_bf16(v[0], v[1]); pk.y = cvt_pk_bf16(v[2], v[3]);
      const int uw = (col >> 3) ^ (r & 7);
      *reinterpret_cast<uint2*>(&Bb[r*64 + uw*8 + (col & 7)]) = pk;
    }
    asm volatile("s_waitcnt lgkmcnt(0)" ::: "memory");
    __builtin_amdgcn_s_barrier();         // Bb published; Wb reads done
    {
      const int r = tid >> 3, u = tid & 7;
      const int phys = u ^ (r & 7);
      u16x8 val = *reinterpret_cast<const u16x8*>(&Bb[r*64 + phys*8]);
      *reinterpret_cast<u16x8*>(outp + (rowBase + r)*512 + c*64 + u*8) = val;
    }
  }
}

// ============ fused MLP v4b (R15-EXACT, passed): 72KB LDS, 2 blocks/CU ============
__global__ __launch_bounds__(512, 4)
void mlp_fused4(const u16* __restrict__ x2, const u16* __restrict__ W1t,
                const u16* __restrict__ W2t, const float* __restrict__ b1,
                const float* __restrict__ b2, float* __restrict__ outF,
                int rowsValid)
{
  __shared__ alignas(16) u16 Xs[64*256];   // 32K: [64 r][32 u], phys = u ^ (r&31)
  __shared__ alignas(16) u16 Wb[16384];    // 32K: W1c [64 hcol][32 u] or W2c [256 ocol][8 u]
  __shared__ alignas(16) u16 Hs[64*64];    //  8K: [64 r][8 u], phys = u ^ (r&7)
  const int tid = threadIdx.x;
  const int wid = tid >> 6, lane = tid & 63;
  const int wm = wid >> 2, wn = wid & 3;   // 2M x 4N
  const int lr = lane & 15, sl = lane >> 4;
  const long rowBase = (long)blockIdx.x * 64;

#pragma unroll
  for (int i = 0; i < 4; ++i) {            // Xs: 2048 units
    const int u = i*512 + tid;
    const int r = u >> 5, pu = u & 31;
    gload_lds16(x2 + (rowBase + r)*256 + ((pu ^ (r & 31)) << 3), &Xs[u*8]);
  }
  auto stageW1 = [&](int c) {              // [64 hcol][256 k] = 32KB
#pragma unroll
    for (int i = 0; i < 4; ++i) {
      const int u = i*512 + tid;
      const int r = u >> 5, pu = u & 31;
      gload_lds16(W1t + (long)(c*64 + r)*256 + ((pu ^ (r & 31)) << 3), &Wb[u*8]);
    }
  };
  auto stageW2 = [&](int c) {              // [256 ocol][64 k] = 32KB
#pragma unroll
    for (int i = 0; i < 4; ++i) {
      const int u = i*512 + tid;
      const int r = u >> 3, pu = u & 7;
      gload_lds16(W2t + (long)r*1024 + c*64 + ((pu ^ (r & 7)) << 3), &Wb[u*8]);
    }
  };
  stageW1(0);
  asm volatile("s_waitcnt vmcnt(0)" ::: "memory");
  __syncthreads();

  f32x4 acc2[2][4] = {};
  for (int c = 0; c < 16; ++c) {
    f32x4 acc1[2] = {};
#pragma unroll
    for (int kk = 0; kk < 8; ++kk) {
      const int u = kk*4 + sl;
      const int rB = wn*16 + lr;
      bf16x8 wb = *reinterpret_cast<const bf16x8*>(&Wb[(rB*32 + (u ^ (rB & 31)))*8]);
#pragma unroll
      for (int mi = 0; mi < 2; ++mi) {
        const int rA = wm*32 + mi*16 + lr;
        bf16x8 xa = *reinterpret_cast<const bf16x8*>(&Xs[(rA*32 + (u ^ (rA & 31)))*8]);
        acc1[mi] = __builtin_amdgcn_mfma_f32_16x16x32_bf16(wb, xa, acc1[mi], 0, 0, 0);
      }
    }
    const float* b1c = b1 + c*64;
#pragma unroll
    for (int mi = 0; mi < 2; ++mi) {
      const int r = wm*32 + mi*16 + lr;
      const int col = wn*16 + sl*4;
      f32x4 v = acc1[mi] + *reinterpret_cast<const f32x4*>(&b1c[col]);
      uint2 pk; pk.x = cvt_pk_bf16(gelu_f(v[0]), gelu_f(v[1]));
      pk.y = cvt_pk_bf16(gelu_f(v[2]), gelu_f(v[3]));
      const int uw = (col >> 3) ^ (r & 7);
      *reinterpret_cast<uint2*>(&Hs[r*64 + uw*8 + (col & 7)]) = pk;
    }
    asm volatile("s_waitcnt lgkmcnt(0)" ::: "memory");
    __builtin_amdgcn_s_barrier();          // Wbuf free (gemm1 reads done) + Hs published
    stageW2(c);
    asm volatile("s_waitcnt vmcnt(0)" ::: "memory");
    __builtin_amdgcn_s_barrier();          // W2c visible to all waves

#pragma unroll
    for (int kk2 = 0; kk2 < 2; ++kk2) {
      const int u = kk2*4 + sl;
      bf16x8 ha[2];
#pragma unroll
      for (int mi = 0; mi < 2; ++mi) {
        const int r = wm*32 + mi*16 + lr;
        ha[mi] = *reinterpret_cast<const bf16x8*>(&Hs[(r*8 + (u ^ (r & 7)))*8]);
      }
#pragma unroll
      for (int nj = 0; nj < 4; ++nj) {
        const int rB = wn*64 + nj*16 + lr;
        bf16x8 wb = *reinterpret_cast<const bf16x8*>(&Wb[(rB*8 + (u ^ (rB & 7)))*8]);
#pragma unroll
        for (int mi = 0; mi < 2; ++mi)
          acc2[mi][nj] = __builtin_amdgcn_mfma_f32_16x16x32_bf16(wb, ha[mi], acc2[mi][nj], 0, 0, 0);
      }
    }
    __builtin_amdgcn_s_barrier();          // Wbuf free (gemm2 reads done)
    if (c + 1 < 16) {
      stageW1(c + 1);
      asm volatile("s_waitcnt vmcnt(0)" ::: "memory");
      __builtin_amdgcn_s_barrier();        // W1(c+1) visible
    }
  }
#pragma unroll
  for (int mi = 0; mi < 2; ++mi) {
    const int r = wm*32 + mi*16 + lr;
    if (rowBase + r < rowsValid) {
      float* orow = outF + (rowBase + r)*256;
#pragma unroll
      for (int nj = 0; nj < 4; ++nj) {
        const int col = wn*64 + nj*16 + sl*4;
        f32x4 v = acc2[mi][nj] + *reinterpret_cast<const f32x4*>(&b2[col])
                + *reinterpret_cast<const f32x4*>(&orow[col]);
        *reinterpret_cast<f32x4*>(&orow[col]) = v;
      }
    }
  }
}

// ---------------- LayerNorm over C=256, one wave per token, bf16 out ----------------
__global__ __launch_bounds__(256)
void ln_kernel(const float* __restrict__ in, const float* __restrict__ g,
               const float* __restrict__ bt, u16* __restrict__ out, int M)
{
  const int wv = threadIdx.x >> 6, lane = threadIdx.x & 63;
  const int t = blockIdx.x * 4 + wv;
  if (t >= M) return;
  const float4 x = reinterpret_cast<const float4*>(in + (long)t*256)[lane];
  float s = x.x + x.y + x.z + x.w;
  float q = x.x*x.x + x.y*x.y + x.z*x.z + x.w*x.w;
#pragma unroll
  for (int o = 32; o > 0; o >>= 1) { s += __shfl_xor(s, o); q += __shfl_xor(q, o); }
  const float m  = s * (1.0f/256.0f);
  const float var = q * (1.0f/256.0f) - m*m;
  const float rs = rsqrtf(var + 1e-5f);
  const float4 gv = reinterpret_cast<const float4*>(g)[lane];
  const float4 bv = reinterpret_cast<const float4*>(bt)[lane];
  uint2 o4;
  o4.x = cvt_pk_bf16((x.x - m)*rs*gv.x + bv.x, (x.y - m)*rs*gv.y + bv.y);
  o4.y = cvt_pk_bf16((x.z - m)*rs*gv.z + bv.z, (x.w - m)*rs*gv.w + bv.w);
  *reinterpret_cast<uint2*>(out + (long)t*256 + lane*4) = o4;
}

// -------- fused per-head LN(k), LN(v) + kv[b,h] += k^T v / N (atomic f32) --------
__global__ __launch_bounds__(256)
void kv_kernel(const u16* __restrict__ KV,
               const float* __restrict__ kg, const float* __restrict__ kb,
               const float* __restrict__ vg, const float* __restrict__ vb,
               float* __restrict__ kvout)
{
  const int bh = blockIdx.x, b = bh >> 3, h = bh & 7;
  const int tid = threadIdx.x;
  __shared__ u16 kls[256][32];
  __shared__ u16 vls[256][32];
  __shared__ float sg[4][32];
  if (tid < 32) {
    sg[0][tid] = kg[h*32 + tid];
    sg[1][tid] = kb[h*32 + tid];
    sg[2][tid] = vg[h*32 + tid];
    sg[3][tid] = vb[h*32 + tid];
  }
  const int d = tid >> 3, e0 = (tid & 7) * 4;
  float a0=0, a1=0, a2=0, a3=0;

  for (int sub = 0; sub < 2; ++sub) {
    const int r = blockIdx.y * 512 + sub * 256 + tid;
    __syncthreads();
    if (r < NTOK) {
      const u16* rowp = KV + (long)(b*NTOK + r)*512;
#pragma unroll
      for (int kv2 = 0; kv2 < 2; ++kv2) {
        const u16* p = rowp + (kv2 ? 256 : 0) + h*32;
        float xv[32]; float s = 0.f;
#pragma unroll
        for (int q4 = 0; q4 < 4; ++q4) {
          u16x8 u = *reinterpret_cast<const u16x8*>(p + q4*8);
#pragma unroll
          for (int j = 0; j < 8; ++j) { float f = bf2f(u[j]); xv[q4*8+j] = f; s += f; }
        }
        const float m = s * (1.0f/32.0f);
        float vv = 0.f;
#pragma unroll
        for (int j = 0; j < 32; ++j) { float d2 = xv[j]-m; vv += d2*d2; }
        const float rs = rsqrtf(vv*(1.0f/32.0f) + 1e-5f);
        const float* gg = sg[kv2 ? 2 : 0];
        const float* bb = sg[kv2 ? 3 : 1];
        u16 (*dst)[32] = kv2 ? vls : kls;
#pragma unroll
        for (int j = 0; j < 32; ++j) dst[tid][j] = f2bf((xv[j]-m)*rs*gg[j] + bb[j]);
      }
    } else {
#pragma unroll
      for (int j = 0; j < 32; ++j) { kls[tid][j] = 0; vls[tid][j] = 0; }
    }
    __syncthreads();
#pragma unroll 4
    for (int rr = 0; rr < 256; ++rr) {
      const float kd = bf2f(kls[rr][d]);
      u16x4 v4 = *reinterpret_cast<const u16x4*>(&vls[rr][e0]);
      a0 += kd * bf2f(v4[0]); a1 += kd * bf2f(v4[1]);
      a2 += kd * bf2f(v4[2]); a3 += kd * bf2f(v4[3]);
    }
  }
  const float sc = 1.0f / (float)NTOK;
  float* o = kvout + (long)bh*1024 + d*32 + e0;
  atomicAdd(o+0, a0*sc); atomicAdd(o+1, a1*sc);
  atomicAdd(o+2, a2*sc); atomicAdd(o+3, a3*sc);
}

// -------- Woe_t[b][c][j=h*32+d] = sum_e kv[b,h,d,e] * Wo[h*32+e][c] --------
__global__ __launch_bounds__(256)
void woeff_kernel(const float* __restrict__ kv, const float* __restrict__ Wo,
                  u16* __restrict__ Woet)
{
  const int b = blockIdx.x >> 8, c = blockIdx.x & 255;
  const int rtid = threadIdx.x;
  const int h = rtid >> 5, dd = rtid & 31;
  const float* kvp = kv + ((long)(b*8 + h)*32 + dd)*32;
  float s = 0.f;
#pragma unroll 8
  for (int e = 0; e < 32; ++e) s += kvp[e] * Wo[(h*32 + e)*256 + c];
  Woet[(long)(b*256 + c)*256 + rtid] = f2bf(s);
}

// -------- Watt[b][c][k] = sum_j Wq[k,j] * kvWo[b][j,c] --------
__global__ __launch_bounds__(256)
void watt_kernel(const u16* __restrict__ wq_bf, const u16* __restrict__ Woet,
                 u16* __restrict__ Watt)
{
  const int b = blockIdx.x >> 8, c = blockIdx.x & 255;
  const int k = threadIdx.x;
  const u16* wr = wq_bf + (long)k*256;
  const u16* er = Woet + ((long)(b*256 + c))*256;
  float s = 0.f;
#pragma unroll 4
  for (int j0 = 0; j0 < 256; j0 += 8) {
    u16x8 wv = *reinterpret_cast<const u16x8*>(wr + j0);
    u16x8 ev = *reinterpret_cast<const u16x8*>(er + j0);
#pragma unroll
    for (int j = 0; j < 8; ++j) s += bf2f(wv[j]) * bf2f(ev[j]);
  }
  Watt[((long)(b*256 + c))*256 + k] = f2bf(s);
}

// -------- be[b][c] = sum_j bq[j] * kvWo[b][j,c] + bo[c] --------
__global__ __launch_bounds__(256)
void be_kernel(const float* __restrict__ bq, const float* __restrict__ bo,
               const u16* __restrict__ Woet, float* __restrict__ be)
{
  const int b = blockIdx.x, c = threadIdx.x;
  const u16* er = Woet + ((long)(b*256 + c))*256;
  float s = bo[c];
#pragma unroll 4
  for (int j0 = 0; j0 < 256; j0 += 8) {
    u16x8 ev = *reinterpret_cast<const u16x8*>(er + j0);
#pragma unroll
    for (int j = 0; j < 8; ++j) s += bq[j0+j] * bf2f(ev[j]);
  }
  be[b*256 + c] = s;
}

// ---------------- mega-prep ----------------
__device__ void transpose_tile(const float* __restrict__ src, u16* __restrict__ dst,
                               int R, int C, int tcx, int trY)
{
  __shared__ float t[32][33];
  const int tc = tcx * 32, tr = trY * 32;
  const int lx = threadIdx.x & 31, ly = threadIdx.x >> 5;
#pragma unroll
  for (int i = 0; i < 32; i += 8)
    t[ly + i][lx] = src[(long)(tr + ly + i)*C + tc + lx];
  __syncthreads();
#pragma unroll
  for (int i = 0; i < 32; i += 8)
    dst[(long)(tc + ly + i)*R + tr + lx] = f2bf(t[lx][ly + i]);
}

__global__ __launch_bounds__(256)
void prep_kernel(const float* __restrict__ Wk, const float* __restrict__ Wv,
                 const float* __restrict__ W1, const float* __restrict__ W2,
                 const float* __restrict__ Wq,
                 const float* __restrict__ bk, const float* __restrict__ bv,
                 u16* __restrict__ Wkv_t, u16* __restrict__ W1_t, u16* __restrict__ W2_t,
                 u16* __restrict__ wq_bf, float* __restrict__ kvb, float* __restrict__ bkv)
{
  int b = blockIdx.x;
  if (b < 256)      { transpose_tile(W1, W1_t, 256, 1024, b & 31, b >> 5); }
  else if (b < 512) { b -= 256; transpose_tile(W2, W2_t, 1024, 256, b & 7, b >> 3); }
  else if (b < 576) { b -= 512; transpose_tile(Wk, Wkv_t,         256, 256, b & 7, b >> 3); }
  else if (b < 640) { b -= 576; transpose_tile(Wv, Wkv_t + 65536, 256, 256, b & 7, b >> 3); }
  else if (b < 648) {
    const int base = (b - 640) * 8192 + threadIdx.x;
#pragma unroll
    for (int i = 0; i < 32; ++i) wq_bf[base + i*256] = f2bf(Wq[base + i*256]);
  } else if (b < 656) {
    const int base = (b - 648) * 8192 + threadIdx.x;
#pragma unroll
    for (int i = 0; i < 32; ++i) kvb[base + i*256] = 0.f;
  } else {
    const int i = threadIdx.x;
    bkv[i] = bk[i]; bkv[256 + i] = bv[i];
  }
}

// ---------------- launch ----------------
extern "C" void kernel_launch(void* const* d_in, const int* in_sizes, int n_in,
                              void* d_out, int out_size, void* d_ws, size_t ws_size,
                              hipStream_t stream)
{
  const float* fx    = (const float*)d_in[0];
  const float* ln1_g = (const float*)d_in[1];
  const float* ln1_b = (const float*)d_in[2];
  const float* Wq = (const float*)d_in[3];
  const float* bq = (const float*)d_in[4];
  const float* Wk = (const float*)d_in[5];
  const float* bk = (const float*)d_in[6];
  const float* Wv = (const float*)d_in[7];
  const float* bv = (const float*)d_in[8];
  const float* Wo = (const float*)d_in[9];
  const float* bo = (const float*)d_in[10];
  const float* kg  = (const float*)d_in[11];
  const float* kbb = (const float*)d_in[12];
  const float* vg  = (const float*)d_in[13];
  const float* vbb = (const float*)d_in[14];
  const float* ln2_g = (const float*)d_in[15];
  const float* ln2_b = (const float*)d_in[16];
  const float* W1 = (const float*)d_in[17];
  const float* b1 = (const float*)d_in[18];
  const float* W2 = (const float*)d_in[19];
  const float* b2 = (const float*)d_in[20];
  float* outF = (float*)d_out;

  char* ws = (char*)d_ws;
  size_t off = 0;
  auto alloc = [&](size_t bytes) { char* p = ws + off; off += (bytes + 255) & ~(size_t)255; return p; };
  u16* bufX   = (u16*)alloc((size_t)MROWS*256*2);   // LN1 out, later x2 (fused LN2 out)
  u16* bufKV  = (u16*)alloc((size_t)MROWS*512*2);
  u16* Wkv_t  = (u16*)alloc(512*256*2);
  u16* W1_t   = (u16*)alloc(1024*256*2);
  u16* W2_t   = (u16*)alloc(256*1024*2);
  u16* Woe_t  = (u16*)alloc((size_t)8*256*256*2);
  u16* Watt   = (u16*)alloc((size_t)8*256*256*2);
  u16* wq_bf  = (u16*)alloc(256*256*2);
  float* kvb  = (float*)alloc((size_t)64*1024*4);
  float* bkv  = (float*)alloc(512*4);
  float* be   = (float*)alloc(8*256*4);
  (void)ws_size; (void)out_size; (void)n_in; (void)in_sizes;

  // prep (single launch)
  prep_kernel<<<657, 256, 0, stream>>>(Wk, Wv, W1, W2, Wq, bk, bv,
                                       Wkv_t, W1_t, W2_t, wq_bf, kvb, bkv);

  // x = LN1(fx)
  ln_kernel<<<MTOT/4, 256, 0, stream>>>(fx, ln1_g, ln1_b, bufX, MTOT);

  // KV = x @ [Wk|Wv] + [bk|bv]  (proj64 UNDER TEST: weight-streamed, 2 blocks/CU)
  proj64<<<MLP_TILES, 512, 0, stream>>>(bufX, Wkv_t, bkv, bufKV);

  // kv[b,h] = LN(k)^T LN(v) / N
  kv_kernel<<<dim3(64, 15), 256, 0, stream>>>(bufKV, kg, kbb, vg, vbb, kvb);

  // kvWo, W_att, be
  woeff_kernel<<<2048, 256, 0, stream>>>(kvb, Wo, Woe_t);
  watt_kernel<<<2048, 256, 0, stream>>>(wq_bf, Woe_t, Watt);
  be_kernel<<<8, 256, 0, stream>>>(bq, bo, Woe_t, be);

  // out = fx + x @ W_att[b] + be[b]  AND  x2 = LN2(out) (fused, EPI 3)
  gemm256<3><<<dim3(MT_BATCH, 1, 8), 512, 0, stream>>>(
      bufX, 256, Watt, 256, 65536, be, 256, fx, outF, 256, 256, NTOK, NTOK,
      ln2_g, ln2_b, bufX);

  // out += gelu(x2 @ W1 + b1) @ W2 + b2   (fused MLP v4b — R15-exact, passed)
  mlp_fused4<<<MLP_TILES, 512, 0, stream>>>(bufX, W1_t, W2_t, b1, b2, outF, MTOT);
}